// Round 1
// baseline (251.496 us; speedup 1.0000x reference)
//
#include <hip/hip_runtime.h>
#include <math.h>

#define WAVE 64
#define XW 13
#define PW 30
#define NBLOCK 2048   // persistent blocks: 256 CU x ~8 waves/CU, grid-stride the rest

// Per-patient derivative. X[13] states, P[30] params (column order per reference).
__device__ __forceinline__ void dxdt(const float* X, const float* P,
                                     float ai, float cho, float lq, float lf,
                                     float* dx)
{
    const float BW = P[0],  KMAX = P[1],  B   = P[2],  D   = P[3],  KMIN = P[4];
    const float KABS = P[5], F   = P[6],  KP1 = P[7],  KP2 = P[8],  KP3  = P[9];
    const float FSNC = P[10], KE1 = P[11], KE2 = P[12], K1 = P[13], K2   = P[14];
    const float VM0 = P[15], VMX = P[16], KM0 = P[17], M1 = P[18], M2   = P[19];
    const float M4  = P[20], KA1 = P[21], KA2 = P[22], VI = P[23], P2U  = P[24];
    const float IB  = P[25], KI  = P[26], M30 = P[27], KD = P[28], KSC  = P[29];

    const float f_insulin = ai * 6000.0f / BW;
    const float qsto = X[0] + X[1];
    const float Dbar = lq + lf;

    dx[0] = -KMAX * X[0] + cho * 1000.0f;

    const float inv_dbar = 1.0f / (Dbar + 1e-7f);
    const float aa = 2.5f / (1.0f - B) * inv_dbar;
    const float cc = 2.5f / D * inv_dbar;
    const float kgut_true = KMIN + (KMAX - KMIN) * 0.5f *
        (tanhf(aa * (qsto - B * Dbar)) - tanhf(cc * (qsto - D * Dbar)) + 2.0f);
    const float kgut = (Dbar > 0.0f) ? kgut_true : KMAX;

    dx[1] = KMAX * X[0] - X[1] * kgut;
    dx[2] = kgut * X[1] - KABS * X[2];

    const float Rat  = F * KABS * X[2] / BW;
    const float EGPt = KP1 - KP2 * X[3] - KP3 * X[8];
    const float Et   = (X[3] > KE2) ? KE1 * (X[3] - KE2) : 0.0f;
    const float d3 = fmaxf(EGPt, 0.0f) + Rat - FSNC - Et - K1 * X[3] + K2 * X[4];
    dx[3] = (X[3] >= 0.0f) ? d3 : 0.0f;

    const float Vmt  = VM0 + VMX * X[6];
    const float Uidt = Vmt * X[4] / (KM0 + X[4]);
    const float d4 = -Uidt + K1 * X[3] - K2 * X[4];
    dx[4] = (X[4] >= 0.0f) ? d4 : 0.0f;

    const float d5 = -(M2 + M4) * X[5] + M1 * X[9] + KA1 * X[10] + KA2 * X[11];
    const float It = X[5] / VI;
    dx[5] = (X[5] >= 0.0f) ? d5 : 0.0f;

    dx[6] = -P2U * X[6] + P2U * (It - IB);
    dx[7] = -KI * (X[7] - It);
    dx[8] = -KI * (X[8] - X[7]);

    const float d9 = -(M1 + M30) * X[9] + M2 * X[5];
    dx[9] = (X[9] >= 0.0f) ? d9 : 0.0f;

    const float d10 = f_insulin - (KA1 + KD) * X[10];
    dx[10] = (X[10] >= 0.0f) ? d10 : 0.0f;

    const float d11 = KD * X[10] - KA2 * X[11];
    dx[11] = (X[11] >= 0.0f) ? d11 : 0.0f;

    const float d12 = -KSC * X[12] + KSC * X[3];
    dx[12] = (X[12] >= 0.0f) ? d12 : 0.0f;
}

// R6: persistent grid-stride + depth-1 software pipeline.
// R5 post-mortem: Occupancy 30%, HBM 22%, VALU 7.5% -> latency/turnaround bound.
// Each 1-wave workgroup kept its 16 KB in flight only for a fraction of its
// lifetime, then died; delivered BW settled at 1.8 TB/s. Here each persistent
// wave prefetches tile t+gridDim's 16 float4s into registers while the
// LDS-transpose/compute/store of tile t runs, so loads stay in flight
// continuously. Single LDS buffer is legal without barriers: same-wave DS ops
// execute in program order (read tile t, then overwrite with tile t+1).
// Spill sentinel: WRITE_SIZE must stay 53248 KiB.
__global__ __launch_bounds__(WAVE, 2) void t1d_kernel(
    const float* __restrict__ x,
    const float* __restrict__ params,
    const float* __restrict__ action_ins,
    const float* __restrict__ action_CHO,
    const float* __restrict__ last_Qsto,
    const float* __restrict__ last_foodtaken,
    float* __restrict__ out, int n)
{
    __shared__ __align__(16) float xb[WAVE * XW];   // 3328 B, doubles as out staging
    __shared__ __align__(16) float pb[WAVE * PW];   // 7680 B

    const int l = threadIdx.x;                       // lane 0..63
    const int ntiles = n / WAVE;                     // full 64-patient tiles
    float4* xl4 = (float4*)xb;
    float4* pl4 = (float4*)pb;

    int t = (int)blockIdx.x;
    if (t < ntiles) {
        // ---- prologue: issue tile t's 16 coalesced float4 loads + 4 scalars ----
        size_t base = (size_t)t * WAVE;
        const float4* xg = (const float4*)(x + base * XW);       // 3328B-aligned
        const float4* pg = (const float4*)(params + base * PW);  // 7680B-aligned
        float4 a0 = xg[l], a1 = xg[l + 64], a2 = xg[l + 128], a3;
        if (l < 16) a3 = xg[192 + l];                            // 208 = 3*64+16
        float4 b0 = pg[l],       b1 = pg[l + 64],  b2 = pg[l + 128];
        float4 b3 = pg[l + 192], b4 = pg[l + 256], b5 = pg[l + 320];
        float4 b6 = pg[l + 384], b7;
        if (l < 32) b7 = pg[448 + l];                            // 480 = 7*64+32
        float ai = action_ins[base + l], cho = action_CHO[base + l];
        float lq = last_Qsto[base + l],  lf = last_foodtaken[base + l];

        #pragma clang loop unroll(disable)
        for (;;) {
            // ---- drain staged regs -> LDS (counted vmcnt waits; loads were
            //      issued a full iteration ago, so these are cheap) ----
            xl4[l]       = a0;
            xl4[l + 64]  = a1;
            xl4[l + 128] = a2;
            if (l < 16) xl4[192 + l] = a3;
            pl4[l]       = b0;
            pl4[l + 64]  = b1;
            pl4[l + 128] = b2;
            pl4[l + 192] = b3;
            pl4[l + 256] = b4;
            pl4[l + 320] = b5;
            pl4[l + 384] = b6;
            if (l < 32) pl4[448 + l] = b7;

            const float  cai = ai, ccho = cho, clq = lq, clf = lf;
            const size_t obase = (size_t)t * WAVE;

            // ---- issue prefetch for tile t+gridDim (overlaps LDS reads,
            //      compute and stores below) ----
            const int  tn   = t + (int)gridDim.x;
            const bool more = tn < ntiles;
            if (more) {
                size_t nb = (size_t)tn * WAVE;
                const float4* xg2 = (const float4*)(x + nb * XW);
                const float4* pg2 = (const float4*)(params + nb * PW);
                a0 = xg2[l]; a1 = xg2[l + 64]; a2 = xg2[l + 128];
                if (l < 16) a3 = xg2[192 + l];
                b0 = pg2[l];       b1 = pg2[l + 64];  b2 = pg2[l + 128];
                b3 = pg2[l + 192]; b4 = pg2[l + 256]; b5 = pg2[l + 320];
                b6 = pg2[l + 384];
                if (l < 32) b7 = pg2[448 + l];
                ai = action_ins[nb + l]; cho = action_CHO[nb + l];
                lq = last_Qsto[nb + l];  lf = last_foodtaken[nb + l];
            }

            // ---- LDS -> per-lane rows (same-wave RAW, lgkm-tracked) ----
            float X[XW], P[PW], dx[XW];
            #pragma unroll
            for (int j = 0; j < XW; ++j) X[j] = xb[l * XW + j];  // stride 13: <=2-way, free
            #pragma unroll
            for (int j = 0; j < PW; ++j) P[j] = pb[l * PW + j];  // stride 30: 4-way, cheap

            dxdt(X, P, cai, ccho, clq, clf, dx);

            // ---- out through LDS x-region (dead until next drain) for
            //      coalesced float4 stores; DS program order makes this safe ----
            #pragma unroll
            for (int j = 0; j < XW; ++j) xb[l * XW + j] = dx[j];
            float4 o0 = xl4[l], o1 = xl4[l + 64], o2 = xl4[l + 128], o3;
            if (l < 16) o3 = xl4[192 + l];
            float4* og = (float4*)(out + obase * XW);
            og[l]       = o0;
            og[l + 64]  = o1;
            og[l + 128] = o2;
            if (l < 16) og[192 + l] = o3;

            if (!more) break;
            t = tn;
        }
    }

    // ---- tail (n % 64 != 0; not hit for N=2^20): grid-stride scalar ----
    const int tail0 = ntiles * WAVE;
    for (int i = tail0 + (int)blockIdx.x * WAVE + l; i < n;
         i += (int)gridDim.x * WAVE) {
        float X[XW], P[PW], dx[XW];
        #pragma unroll
        for (int j = 0; j < XW; ++j) X[j] = x[(size_t)i * XW + j];
        #pragma unroll
        for (int j = 0; j < PW; ++j) P[j] = params[(size_t)i * PW + j];
        dxdt(X, P, action_ins[i], action_CHO[i], last_Qsto[i],
             last_foodtaken[i], dx);
        #pragma unroll
        for (int j = 0; j < XW; ++j) out[(size_t)i * XW + j] = dx[j];
    }
}

extern "C" void kernel_launch(void* const* d_in, const int* in_sizes, int n_in,
                              void* d_out, int out_size, void* d_ws, size_t ws_size,
                              hipStream_t stream) {
    const float* x      = (const float*)d_in[0];
    const float* params = (const float*)d_in[1];
    const float* ai     = (const float*)d_in[2];
    const float* cho    = (const float*)d_in[3];
    const float* lq     = (const float*)d_in[4];
    const float* lf     = (const float*)d_in[5];
    float* out = (float*)d_out;

    const int n = in_sizes[0] / XW;          // number of patients
    const int ntiles = n / WAVE;
    int grid = ntiles > 0 ? (ntiles < NBLOCK ? ntiles : NBLOCK) : 1;
    t1d_kernel<<<grid, WAVE, 0, stream>>>(x, params, ai, cho, lq, lf, out, n);
}

// Round 2
// 250.042 us; speedup vs baseline: 1.0058x; 1.0058x over previous
//
#include <hip/hip_runtime.h>
#include <math.h>

#define WAVE 64
#define XW 13
#define PW 30
// R7: 3584 = 14 blocks/CU x 256 CU — the LDS residency limit (160 KiB / 11.25 KiB).
// R6's 2048 (8/CU) was the binding constraint: same 1.75 TB/s as R5 with half the
// waves proved the pipeline works but parallelism was cut. Scale waves back up.
#define NBLOCK 3584

// Per-patient derivative. X[13] states, P[30] params (column order per reference).
__device__ __forceinline__ void dxdt(const float* X, const float* P,
                                     float ai, float cho, float lq, float lf,
                                     float* dx)
{
    const float BW = P[0],  KMAX = P[1],  B   = P[2],  D   = P[3],  KMIN = P[4];
    const float KABS = P[5], F   = P[6],  KP1 = P[7],  KP2 = P[8],  KP3  = P[9];
    const float FSNC = P[10], KE1 = P[11], KE2 = P[12], K1 = P[13], K2   = P[14];
    const float VM0 = P[15], VMX = P[16], KM0 = P[17], M1 = P[18], M2   = P[19];
    const float M4  = P[20], KA1 = P[21], KA2 = P[22], VI = P[23], P2U  = P[24];
    const float IB  = P[25], KI  = P[26], M30 = P[27], KD = P[28], KSC  = P[29];

    const float f_insulin = ai * 6000.0f / BW;
    const float qsto = X[0] + X[1];
    const float Dbar = lq + lf;

    dx[0] = -KMAX * X[0] + cho * 1000.0f;

    const float inv_dbar = 1.0f / (Dbar + 1e-7f);
    const float aa = 2.5f / (1.0f - B) * inv_dbar;
    const float cc = 2.5f / D * inv_dbar;
    const float kgut_true = KMIN + (KMAX - KMIN) * 0.5f *
        (tanhf(aa * (qsto - B * Dbar)) - tanhf(cc * (qsto - D * Dbar)) + 2.0f);
    const float kgut = (Dbar > 0.0f) ? kgut_true : KMAX;

    dx[1] = KMAX * X[0] - X[1] * kgut;
    dx[2] = kgut * X[1] - KABS * X[2];

    const float Rat  = F * KABS * X[2] / BW;
    const float EGPt = KP1 - KP2 * X[3] - KP3 * X[8];
    const float Et   = (X[3] > KE2) ? KE1 * (X[3] - KE2) : 0.0f;
    const float d3 = fmaxf(EGPt, 0.0f) + Rat - FSNC - Et - K1 * X[3] + K2 * X[4];
    dx[3] = (X[3] >= 0.0f) ? d3 : 0.0f;

    const float Vmt  = VM0 + VMX * X[6];
    const float Uidt = Vmt * X[4] / (KM0 + X[4]);
    const float d4 = -Uidt + K1 * X[3] - K2 * X[4];
    dx[4] = (X[4] >= 0.0f) ? d4 : 0.0f;

    const float d5 = -(M2 + M4) * X[5] + M1 * X[9] + KA1 * X[10] + KA2 * X[11];
    const float It = X[5] / VI;
    dx[5] = (X[5] >= 0.0f) ? d5 : 0.0f;

    dx[6] = -P2U * X[6] + P2U * (It - IB);
    dx[7] = -KI * (X[7] - It);
    dx[8] = -KI * (X[8] - X[7]);

    const float d9 = -(M1 + M30) * X[9] + M2 * X[5];
    dx[9] = (X[9] >= 0.0f) ? d9 : 0.0f;

    const float d10 = f_insulin - (KA1 + KD) * X[10];
    dx[10] = (X[10] >= 0.0f) ? d10 : 0.0f;

    const float d11 = KD * X[10] - KA2 * X[11];
    dx[11] = (X[11] >= 0.0f) ? d11 : 0.0f;

    const float d12 = -KSC * X[12] + KSC * X[3];
    dx[12] = (X[12] >= 0.0f) ? d12 : 0.0f;
}

// R7: persistent grid-stride + depth-1 software pipeline (unchanged from R6),
// grid raised to the LDS residency limit (14 one-wave blocks/CU).
// R6 post-mortem: BW 1.75 TB/s at 5.2 waves/CU == R5's 1.78 at 9.6 waves/CU
// -> pipeline doubled per-wave throughput; parallelism was the new binding
// constraint. Single LDS buffer, no barriers: same-wave DS ops are program-
// ordered. Spill sentinel: WRITE_SIZE must stay 53248 KiB, VGPR ~64.
__global__ __launch_bounds__(WAVE, 2) void t1d_kernel(
    const float* __restrict__ x,
    const float* __restrict__ params,
    const float* __restrict__ action_ins,
    const float* __restrict__ action_CHO,
    const float* __restrict__ last_Qsto,
    const float* __restrict__ last_foodtaken,
    float* __restrict__ out, int n)
{
    __shared__ __align__(16) float xb[WAVE * XW];   // 3328 B, doubles as out staging
    __shared__ __align__(16) float pb[WAVE * PW];   // 7680 B

    const int l = threadIdx.x;                       // lane 0..63
    const int ntiles = n / WAVE;                     // full 64-patient tiles
    float4* xl4 = (float4*)xb;
    float4* pl4 = (float4*)pb;

    int t = (int)blockIdx.x;
    if (t < ntiles) {
        // ---- prologue: issue tile t's 16 coalesced float4 loads + 4 scalars ----
        size_t base = (size_t)t * WAVE;
        const float4* xg = (const float4*)(x + base * XW);       // 3328B-aligned
        const float4* pg = (const float4*)(params + base * PW);  // 7680B-aligned
        float4 a0 = xg[l], a1 = xg[l + 64], a2 = xg[l + 128], a3;
        if (l < 16) a3 = xg[192 + l];                            // 208 = 3*64+16
        float4 b0 = pg[l],       b1 = pg[l + 64],  b2 = pg[l + 128];
        float4 b3 = pg[l + 192], b4 = pg[l + 256], b5 = pg[l + 320];
        float4 b6 = pg[l + 384], b7;
        if (l < 32) b7 = pg[448 + l];                            // 480 = 7*64+32
        float ai = action_ins[base + l], cho = action_CHO[base + l];
        float lq = last_Qsto[base + l],  lf = last_foodtaken[base + l];

        #pragma clang loop unroll(disable)
        for (;;) {
            // ---- drain staged regs -> LDS (counted vmcnt waits; loads were
            //      issued a full iteration ago, so these are cheap) ----
            xl4[l]       = a0;
            xl4[l + 64]  = a1;
            xl4[l + 128] = a2;
            if (l < 16) xl4[192 + l] = a3;
            pl4[l]       = b0;
            pl4[l + 64]  = b1;
            pl4[l + 128] = b2;
            pl4[l + 192] = b3;
            pl4[l + 256] = b4;
            pl4[l + 320] = b5;
            pl4[l + 384] = b6;
            if (l < 32) pl4[448 + l] = b7;

            const float  cai = ai, ccho = cho, clq = lq, clf = lf;
            const size_t obase = (size_t)t * WAVE;

            // ---- issue prefetch for tile t+gridDim (overlaps LDS reads,
            //      compute and stores below) ----
            const int  tn   = t + (int)gridDim.x;
            const bool more = tn < ntiles;
            if (more) {
                size_t nb = (size_t)tn * WAVE;
                const float4* xg2 = (const float4*)(x + nb * XW);
                const float4* pg2 = (const float4*)(params + nb * PW);
                a0 = xg2[l]; a1 = xg2[l + 64]; a2 = xg2[l + 128];
                if (l < 16) a3 = xg2[192 + l];
                b0 = pg2[l];       b1 = pg2[l + 64];  b2 = pg2[l + 128];
                b3 = pg2[l + 192]; b4 = pg2[l + 256]; b5 = pg2[l + 320];
                b6 = pg2[l + 384];
                if (l < 32) b7 = pg2[448 + l];
                ai = action_ins[nb + l]; cho = action_CHO[nb + l];
                lq = last_Qsto[nb + l];  lf = last_foodtaken[nb + l];
            }

            // ---- LDS -> per-lane rows (same-wave RAW, lgkm-tracked) ----
            float X[XW], P[PW], dx[XW];
            #pragma unroll
            for (int j = 0; j < XW; ++j) X[j] = xb[l * XW + j];  // stride 13: <=2-way, free
            #pragma unroll
            for (int j = 0; j < PW; ++j) P[j] = pb[l * PW + j];  // stride 30: 4-way, cheap

            dxdt(X, P, cai, ccho, clq, clf, dx);

            // ---- out through LDS x-region (dead until next drain) for
            //      coalesced float4 stores; DS program order makes this safe ----
            #pragma unroll
            for (int j = 0; j < XW; ++j) xb[l * XW + j] = dx[j];
            float4 o0 = xl4[l], o1 = xl4[l + 64], o2 = xl4[l + 128], o3;
            if (l < 16) o3 = xl4[192 + l];
            float4* og = (float4*)(out + obase * XW);
            og[l]       = o0;
            og[l + 64]  = o1;
            og[l + 128] = o2;
            if (l < 16) og[192 + l] = o3;

            if (!more) break;
            t = tn;
        }
    }

    // ---- tail (n % 64 != 0; not hit for N=2^20): grid-stride scalar ----
    const int tail0 = ntiles * WAVE;
    for (int i = tail0 + (int)blockIdx.x * WAVE + l; i < n;
         i += (int)gridDim.x * WAVE) {
        float X[XW], P[PW], dx[XW];
        #pragma unroll
        for (int j = 0; j < XW; ++j) X[j] = x[(size_t)i * XW + j];
        #pragma unroll
        for (int j = 0; j < PW; ++j) P[j] = params[(size_t)i * PW + j];
        dxdt(X, P, action_ins[i], action_CHO[i], last_Qsto[i],
             last_foodtaken[i], dx);
        #pragma unroll
        for (int j = 0; j < XW; ++j) out[(size_t)i * XW + j] = dx[j];
    }
}

extern "C" void kernel_launch(void* const* d_in, const int* in_sizes, int n_in,
                              void* d_out, int out_size, void* d_ws, size_t ws_size,
                              hipStream_t stream) {
    const float* x      = (const float*)d_in[0];
    const float* params = (const float*)d_in[1];
    const float* ai     = (const float*)d_in[2];
    const float* cho    = (const float*)d_in[3];
    const float* lq     = (const float*)d_in[4];
    const float* lf     = (const float*)d_in[5];
    float* out = (float*)d_out;

    const int n = in_sizes[0] / XW;          // number of patients
    const int ntiles = n / WAVE;
    int grid = ntiles > 0 ? (ntiles < NBLOCK ? ntiles : NBLOCK) : 1;
    t1d_kernel<<<grid, WAVE, 0, stream>>>(x, params, ai, cho, lq, lf, out, n);
}

// Round 5
// 239.146 us; speedup vs baseline: 1.0516x; 1.0456x over previous
//
#include <hip/hip_runtime.h>
#include <math.h>

#define WAVE 64
#define XW 13
#define PW 30
// R7 showed occupancy is NOT the lever (BW flat 1.72-1.78 TB/s across 5.2-9.6
// waves/CU). Keep 3584 (14 blocks/CU LDS cap); don't chase residency further.
#define NBLOCK 3584

// clang native vector: required by __builtin_nontemporal_load/store (R8's
// compile failure: HIP_vector_type float4 is rejected). Same 16B codegen.
typedef float f4 __attribute__((ext_vector_type(4)));

// Per-patient derivative. X[13] states, P[30] params (column order per reference).
__device__ __forceinline__ void dxdt(const float* X, const float* P,
                                     float ai, float cho, float lq, float lf,
                                     float* dx)
{
    const float BW = P[0],  KMAX = P[1],  B   = P[2],  D   = P[3],  KMIN = P[4];
    const float KABS = P[5], F   = P[6],  KP1 = P[7],  KP2 = P[8],  KP3  = P[9];
    const float FSNC = P[10], KE1 = P[11], KE2 = P[12], K1 = P[13], K2   = P[14];
    const float VM0 = P[15], VMX = P[16], KM0 = P[17], M1 = P[18], M2   = P[19];
    const float M4  = P[20], KA1 = P[21], KA2 = P[22], VI = P[23], P2U  = P[24];
    const float IB  = P[25], KI  = P[26], M30 = P[27], KD = P[28], KSC  = P[29];

    const float f_insulin = ai * 6000.0f / BW;
    const float qsto = X[0] + X[1];
    const float Dbar = lq + lf;

    dx[0] = -KMAX * X[0] + cho * 1000.0f;

    const float inv_dbar = 1.0f / (Dbar + 1e-7f);
    const float aa = 2.5f / (1.0f - B) * inv_dbar;
    const float cc = 2.5f / D * inv_dbar;
    const float kgut_true = KMIN + (KMAX - KMIN) * 0.5f *
        (tanhf(aa * (qsto - B * Dbar)) - tanhf(cc * (qsto - D * Dbar)) + 2.0f);
    const float kgut = (Dbar > 0.0f) ? kgut_true : KMAX;

    dx[1] = KMAX * X[0] - X[1] * kgut;
    dx[2] = kgut * X[1] - KABS * X[2];

    const float Rat  = F * KABS * X[2] / BW;
    const float EGPt = KP1 - KP2 * X[3] - KP3 * X[8];
    const float Et   = (X[3] > KE2) ? KE1 * (X[3] - KE2) : 0.0f;
    const float d3 = fmaxf(EGPt, 0.0f) + Rat - FSNC - Et - K1 * X[3] + K2 * X[4];
    dx[3] = (X[3] >= 0.0f) ? d3 : 0.0f;

    const float Vmt  = VM0 + VMX * X[6];
    const float Uidt = Vmt * X[4] / (KM0 + X[4]);
    const float d4 = -Uidt + K1 * X[3] - K2 * X[4];
    dx[4] = (X[4] >= 0.0f) ? d4 : 0.0f;

    const float d5 = -(M2 + M4) * X[5] + M1 * X[9] + KA1 * X[10] + KA2 * X[11];
    const float It = X[5] / VI;
    dx[5] = (X[5] >= 0.0f) ? d5 : 0.0f;

    dx[6] = -P2U * X[6] + P2U * (It - IB);
    dx[7] = -KI * (X[7] - It);
    dx[8] = -KI * (X[8] - X[7]);

    const float d9 = -(M1 + M30) * X[9] + M2 * X[5];
    dx[9] = (X[9] >= 0.0f) ? d9 : 0.0f;

    const float d10 = f_insulin - (KA1 + KD) * X[10];
    dx[10] = (X[10] >= 0.0f) ? d10 : 0.0f;

    const float d11 = KD * X[10] - KA2 * X[11];
    dx[11] = (X[11] >= 0.0f) ? d11 : 0.0f;

    const float d12 = -KSC * X[12] + KSC * X[3];
    dx[12] = (X[12] >= 0.0f) ? d12 : 0.0f;
}

// R10 = R9 resubmitted verbatim (R9 never ran: container infra failure).
// Stream-partition the L3: R5-R7 proved BW pinned at ~1.75 TB/s HBM regardless
// of occupancy (5.2-9.6 waves/CU) and pipelining -> saturated shared server.
// Working set (252 MB) == L3 capacity (256 MB) -> ~50% capacity misses scatter
// the HBM request stream (~27% DRAM efficiency == measured 1.73/6.3). Fix:
// params reads (125.8 MB) and out writes (54.5 MB) NONTEMPORAL so they stream
// sequentially past L3; x + 4 scalar arrays (71 MB) stay cached in L3 ~100%.
// Spill sentinel: WRITE_SIZE must stay 53248 KiB, VGPR ~64.
__global__ __launch_bounds__(WAVE, 2) void t1d_kernel(
    const float* __restrict__ x,
    const float* __restrict__ params,
    const float* __restrict__ action_ins,
    const float* __restrict__ action_CHO,
    const float* __restrict__ last_Qsto,
    const float* __restrict__ last_foodtaken,
    float* __restrict__ out, int n)
{
    __shared__ __align__(16) float xb[WAVE * XW];   // 3328 B, doubles as out staging
    __shared__ __align__(16) float pb[WAVE * PW];   // 7680 B

    const int l = threadIdx.x;                       // lane 0..63
    const int ntiles = n / WAVE;                     // full 64-patient tiles
    f4* xl4 = (f4*)xb;
    f4* pl4 = (f4*)pb;

    int t = (int)blockIdx.x;
    if (t < ntiles) {
        // ---- prologue: issue tile t's 16 coalesced 16B loads + 4 scalars ----
        size_t base = (size_t)t * WAVE;
        const f4* xg = (const f4*)(x + base * XW);       // 3328B-aligned
        const f4* pg = (const f4*)(params + base * PW);  // 7680B-aligned
        f4 a0 = xg[l], a1 = xg[l + 64], a2 = xg[l + 128], a3;
        if (l < 16) a3 = xg[192 + l];                    // 208 = 3*64+16
        f4 b0 = __builtin_nontemporal_load(pg + l);
        f4 b1 = __builtin_nontemporal_load(pg + l + 64);
        f4 b2 = __builtin_nontemporal_load(pg + l + 128);
        f4 b3 = __builtin_nontemporal_load(pg + l + 192);
        f4 b4 = __builtin_nontemporal_load(pg + l + 256);
        f4 b5 = __builtin_nontemporal_load(pg + l + 320);
        f4 b6 = __builtin_nontemporal_load(pg + l + 384);
        f4 b7;
        if (l < 32) b7 = __builtin_nontemporal_load(pg + 448 + l); // 480 = 7*64+32
        float ai = action_ins[base + l], cho = action_CHO[base + l];
        float lq = last_Qsto[base + l],  lf = last_foodtaken[base + l];

        #pragma clang loop unroll(disable)
        for (;;) {
            // ---- drain staged regs -> LDS (counted vmcnt waits; loads were
            //      issued a full iteration ago, so these are cheap) ----
            xl4[l]       = a0;
            xl4[l + 64]  = a1;
            xl4[l + 128] = a2;
            if (l < 16) xl4[192 + l] = a3;
            pl4[l]       = b0;
            pl4[l + 64]  = b1;
            pl4[l + 128] = b2;
            pl4[l + 192] = b3;
            pl4[l + 256] = b4;
            pl4[l + 320] = b5;
            pl4[l + 384] = b6;
            if (l < 32) pl4[448 + l] = b7;

            const float  cai = ai, ccho = cho, clq = lq, clf = lf;
            const size_t obase = (size_t)t * WAVE;

            // ---- issue prefetch for tile t+gridDim (overlaps LDS reads,
            //      compute and stores below) ----
            const int  tn   = t + (int)gridDim.x;
            const bool more = tn < ntiles;
            if (more) {
                size_t nb = (size_t)tn * WAVE;
                const f4* xg2 = (const f4*)(x + nb * XW);
                const f4* pg2 = (const f4*)(params + nb * PW);
                a0 = xg2[l]; a1 = xg2[l + 64]; a2 = xg2[l + 128];
                if (l < 16) a3 = xg2[192 + l];
                b0 = __builtin_nontemporal_load(pg2 + l);
                b1 = __builtin_nontemporal_load(pg2 + l + 64);
                b2 = __builtin_nontemporal_load(pg2 + l + 128);
                b3 = __builtin_nontemporal_load(pg2 + l + 192);
                b4 = __builtin_nontemporal_load(pg2 + l + 256);
                b5 = __builtin_nontemporal_load(pg2 + l + 320);
                b6 = __builtin_nontemporal_load(pg2 + l + 384);
                if (l < 32) b7 = __builtin_nontemporal_load(pg2 + 448 + l);
                ai = action_ins[nb + l]; cho = action_CHO[nb + l];
                lq = last_Qsto[nb + l];  lf = last_foodtaken[nb + l];
            }

            // ---- LDS -> per-lane rows (same-wave RAW, lgkm-tracked) ----
            float X[XW], P[PW], dx[XW];
            #pragma unroll
            for (int j = 0; j < XW; ++j) X[j] = xb[l * XW + j];  // stride 13: <=2-way, free
            #pragma unroll
            for (int j = 0; j < PW; ++j) P[j] = pb[l * PW + j];  // stride 30: 4-way, cheap

            dxdt(X, P, cai, ccho, clq, clf, dx);

            // ---- out through LDS x-region (dead until next drain) for
            //      coalesced 16B stores; DS program order makes this safe ----
            #pragma unroll
            for (int j = 0; j < XW; ++j) xb[l * XW + j] = dx[j];
            f4 o0 = xl4[l], o1 = xl4[l + 64], o2 = xl4[l + 128], o3;
            if (l < 16) o3 = xl4[192 + l];
            f4* og = (f4*)(out + obase * XW);
            __builtin_nontemporal_store(o0, og + l);
            __builtin_nontemporal_store(o1, og + l + 64);
            __builtin_nontemporal_store(o2, og + l + 128);
            if (l < 16) __builtin_nontemporal_store(o3, og + 192 + l);

            if (!more) break;
            t = tn;
        }
    }

    // ---- tail (n % 64 != 0; not hit for N=2^20): grid-stride scalar ----
    const int tail0 = ntiles * WAVE;
    for (int i = tail0 + (int)blockIdx.x * WAVE + l; i < n;
         i += (int)gridDim.x * WAVE) {
        float X[XW], P[PW], dx[XW];
        #pragma unroll
        for (int j = 0; j < XW; ++j) X[j] = x[(size_t)i * XW + j];
        #pragma unroll
        for (int j = 0; j < PW; ++j) P[j] = params[(size_t)i * PW + j];
        dxdt(X, P, action_ins[i], action_CHO[i], last_Qsto[i],
             last_foodtaken[i], dx);
        #pragma unroll
        for (int j = 0; j < XW; ++j) out[(size_t)i * XW + j] = dx[j];
    }
}

extern "C" void kernel_launch(void* const* d_in, const int* in_sizes, int n_in,
                              void* d_out, int out_size, void* d_ws, size_t ws_size,
                              hipStream_t stream) {
    const float* x      = (const float*)d_in[0];
    const float* params = (const float*)d_in[1];
    const float* ai     = (const float*)d_in[2];
    const float* cho    = (const float*)d_in[3];
    const float* lq     = (const float*)d_in[4];
    const float* lf     = (const float*)d_in[5];
    float* out = (float*)d_out;

    const int n = in_sizes[0] / XW;          // number of patients
    const int ntiles = n / WAVE;
    int grid = ntiles > 0 ? (ntiles < NBLOCK ? ntiles : NBLOCK) : 1;
    t1d_kernel<<<grid, WAVE, 0, stream>>>(x, params, ai, cho, lq, lf, out, n);
}

// Round 6
// 234.413 us; speedup vs baseline: 1.0729x; 1.0202x over previous
//
#include <hip/hip_runtime.h>
#include <math.h>

#define WAVE 64
#define XW 13
#define PW 30
// R7: occupancy is NOT the lever (BW flat across 5.2-9.6 waves/CU).
// Keep 3584 (14 one-wave blocks/CU, the 160KiB/11.25KiB LDS residency cap).
#define NBLOCK 3584

// clang native vector: required by __builtin_nontemporal_load/store
// (HIP_vector_type float4 is rejected). Same 16B codegen.
typedef float f4 __attribute__((ext_vector_type(4)));

// Per-patient derivative. X[13] states, P[30] params (column order per reference).
__device__ __forceinline__ void dxdt(const float* X, const float* P,
                                     float ai, float cho, float lq, float lf,
                                     float* dx)
{
    const float BW = P[0],  KMAX = P[1],  B   = P[2],  D   = P[3],  KMIN = P[4];
    const float KABS = P[5], F   = P[6],  KP1 = P[7],  KP2 = P[8],  KP3  = P[9];
    const float FSNC = P[10], KE1 = P[11], KE2 = P[12], K1 = P[13], K2   = P[14];
    const float VM0 = P[15], VMX = P[16], KM0 = P[17], M1 = P[18], M2   = P[19];
    const float M4  = P[20], KA1 = P[21], KA2 = P[22], VI = P[23], P2U  = P[24];
    const float IB  = P[25], KI  = P[26], M30 = P[27], KD = P[28], KSC  = P[29];

    const float f_insulin = ai * 6000.0f / BW;
    const float qsto = X[0] + X[1];
    const float Dbar = lq + lf;

    dx[0] = -KMAX * X[0] + cho * 1000.0f;

    const float inv_dbar = 1.0f / (Dbar + 1e-7f);
    const float aa = 2.5f / (1.0f - B) * inv_dbar;
    const float cc = 2.5f / D * inv_dbar;
    const float kgut_true = KMIN + (KMAX - KMIN) * 0.5f *
        (tanhf(aa * (qsto - B * Dbar)) - tanhf(cc * (qsto - D * Dbar)) + 2.0f);
    const float kgut = (Dbar > 0.0f) ? kgut_true : KMAX;

    dx[1] = KMAX * X[0] - X[1] * kgut;
    dx[2] = kgut * X[1] - KABS * X[2];

    const float Rat  = F * KABS * X[2] / BW;
    const float EGPt = KP1 - KP2 * X[3] - KP3 * X[8];
    const float Et   = (X[3] > KE2) ? KE1 * (X[3] - KE2) : 0.0f;
    const float d3 = fmaxf(EGPt, 0.0f) + Rat - FSNC - Et - K1 * X[3] + K2 * X[4];
    dx[3] = (X[3] >= 0.0f) ? d3 : 0.0f;

    const float Vmt  = VM0 + VMX * X[6];
    const float Uidt = Vmt * X[4] / (KM0 + X[4]);
    const float d4 = -Uidt + K1 * X[3] - K2 * X[4];
    dx[4] = (X[4] >= 0.0f) ? d4 : 0.0f;

    const float d5 = -(M2 + M4) * X[5] + M1 * X[9] + KA1 * X[10] + KA2 * X[11];
    const float It = X[5] / VI;
    dx[5] = (X[5] >= 0.0f) ? d5 : 0.0f;

    dx[6] = -P2U * X[6] + P2U * (It - IB);
    dx[7] = -KI * (X[7] - It);
    dx[8] = -KI * (X[8] - X[7]);

    const float d9 = -(M1 + M30) * X[9] + M2 * X[5];
    dx[9] = (X[9] >= 0.0f) ? d9 : 0.0f;

    const float d10 = f_insulin - (KA1 + KD) * X[10];
    dx[10] = (X[10] >= 0.0f) ? d10 : 0.0f;

    const float d11 = KD * X[10] - KA2 * X[11];
    dx[11] = (X[11] >= 0.0f) ? d11 : 0.0f;

    const float d12 = -KSC * X[12] + KSC * X[3];
    dx[12] = (X[12] >= 0.0f) ? d12 : 0.0f;
}

// R11 = R10 + nontemporal on the REMAINING streams (x + 4 scalar arrays).
// R10 (params+out nt) cut t1d from 88us to <73us (fell out of top-5; fills at
// 73us now dominate). Same-session fillBuffer hits 6.85 TB/s -> the memory
// system delivers 86% of peak for sequential traffic; we're at ~3.5 TB/s.
// Model: L3 is memory-side; nt reads still HIT dirty lines (reset's 503 MB
// fill leaves inputs L3-resident) but stop ALLOCATING on miss -> no victim
// writebacks interleaved into the HBM stream -> higher DRAM efficiency.
// R11 completes the nt coverage: 100% of kernel traffic is now no-allocate.
// Spill sentinel: WRITE_SIZE must stay 53248 KiB, VGPR ~64.
__global__ __launch_bounds__(WAVE, 2) void t1d_kernel(
    const float* __restrict__ x,
    const float* __restrict__ params,
    const float* __restrict__ action_ins,
    const float* __restrict__ action_CHO,
    const float* __restrict__ last_Qsto,
    const float* __restrict__ last_foodtaken,
    float* __restrict__ out, int n)
{
    __shared__ __align__(16) float xb[WAVE * XW];   // 3328 B, doubles as out staging
    __shared__ __align__(16) float pb[WAVE * PW];   // 7680 B

    const int l = threadIdx.x;                       // lane 0..63
    const int ntiles = n / WAVE;                     // full 64-patient tiles
    f4* xl4 = (f4*)xb;
    f4* pl4 = (f4*)pb;

    int t = (int)blockIdx.x;
    if (t < ntiles) {
        // ---- prologue: issue tile t's 16 coalesced 16B loads + 4 scalars ----
        size_t base = (size_t)t * WAVE;
        const f4* xg = (const f4*)(x + base * XW);       // 3328B-aligned
        const f4* pg = (const f4*)(params + base * PW);  // 7680B-aligned
        f4 a0 = __builtin_nontemporal_load(xg + l);
        f4 a1 = __builtin_nontemporal_load(xg + l + 64);
        f4 a2 = __builtin_nontemporal_load(xg + l + 128);
        f4 a3;
        if (l < 16) a3 = __builtin_nontemporal_load(xg + 192 + l); // 208 = 3*64+16
        f4 b0 = __builtin_nontemporal_load(pg + l);
        f4 b1 = __builtin_nontemporal_load(pg + l + 64);
        f4 b2 = __builtin_nontemporal_load(pg + l + 128);
        f4 b3 = __builtin_nontemporal_load(pg + l + 192);
        f4 b4 = __builtin_nontemporal_load(pg + l + 256);
        f4 b5 = __builtin_nontemporal_load(pg + l + 320);
        f4 b6 = __builtin_nontemporal_load(pg + l + 384);
        f4 b7;
        if (l < 32) b7 = __builtin_nontemporal_load(pg + 448 + l); // 480 = 7*64+32
        float ai  = __builtin_nontemporal_load(action_ins + base + l);
        float cho = __builtin_nontemporal_load(action_CHO + base + l);
        float lq  = __builtin_nontemporal_load(last_Qsto + base + l);
        float lf  = __builtin_nontemporal_load(last_foodtaken + base + l);

        #pragma clang loop unroll(disable)
        for (;;) {
            // ---- drain staged regs -> LDS (counted vmcnt waits; loads were
            //      issued a full iteration ago, so these are cheap) ----
            xl4[l]       = a0;
            xl4[l + 64]  = a1;
            xl4[l + 128] = a2;
            if (l < 16) xl4[192 + l] = a3;
            pl4[l]       = b0;
            pl4[l + 64]  = b1;
            pl4[l + 128] = b2;
            pl4[l + 192] = b3;
            pl4[l + 256] = b4;
            pl4[l + 320] = b5;
            pl4[l + 384] = b6;
            if (l < 32) pl4[448 + l] = b7;

            const float  cai = ai, ccho = cho, clq = lq, clf = lf;
            const size_t obase = (size_t)t * WAVE;

            // ---- issue prefetch for tile t+gridDim (overlaps LDS reads,
            //      compute and stores below) ----
            const int  tn   = t + (int)gridDim.x;
            const bool more = tn < ntiles;
            if (more) {
                size_t nb = (size_t)tn * WAVE;
                const f4* xg2 = (const f4*)(x + nb * XW);
                const f4* pg2 = (const f4*)(params + nb * PW);
                a0 = __builtin_nontemporal_load(xg2 + l);
                a1 = __builtin_nontemporal_load(xg2 + l + 64);
                a2 = __builtin_nontemporal_load(xg2 + l + 128);
                if (l < 16) a3 = __builtin_nontemporal_load(xg2 + 192 + l);
                b0 = __builtin_nontemporal_load(pg2 + l);
                b1 = __builtin_nontemporal_load(pg2 + l + 64);
                b2 = __builtin_nontemporal_load(pg2 + l + 128);
                b3 = __builtin_nontemporal_load(pg2 + l + 192);
                b4 = __builtin_nontemporal_load(pg2 + l + 256);
                b5 = __builtin_nontemporal_load(pg2 + l + 320);
                b6 = __builtin_nontemporal_load(pg2 + l + 384);
                if (l < 32) b7 = __builtin_nontemporal_load(pg2 + 448 + l);
                ai  = __builtin_nontemporal_load(action_ins + nb + l);
                cho = __builtin_nontemporal_load(action_CHO + nb + l);
                lq  = __builtin_nontemporal_load(last_Qsto + nb + l);
                lf  = __builtin_nontemporal_load(last_foodtaken + nb + l);
            }

            // ---- LDS -> per-lane rows (same-wave RAW, lgkm-tracked) ----
            float X[XW], P[PW], dx[XW];
            #pragma unroll
            for (int j = 0; j < XW; ++j) X[j] = xb[l * XW + j];  // stride 13: <=2-way, free
            #pragma unroll
            for (int j = 0; j < PW; ++j) P[j] = pb[l * PW + j];  // stride 30: 4-way, cheap

            dxdt(X, P, cai, ccho, clq, clf, dx);

            // ---- out through LDS x-region (dead until next drain) for
            //      coalesced 16B stores; DS program order makes this safe ----
            #pragma unroll
            for (int j = 0; j < XW; ++j) xb[l * XW + j] = dx[j];
            f4 o0 = xl4[l], o1 = xl4[l + 64], o2 = xl4[l + 128], o3;
            if (l < 16) o3 = xl4[192 + l];
            f4* og = (f4*)(out + obase * XW);
            __builtin_nontemporal_store(o0, og + l);
            __builtin_nontemporal_store(o1, og + l + 64);
            __builtin_nontemporal_store(o2, og + l + 128);
            if (l < 16) __builtin_nontemporal_store(o3, og + 192 + l);

            if (!more) break;
            t = tn;
        }
    }

    // ---- tail (n % 64 != 0; not hit for N=2^20): grid-stride scalar ----
    const int tail0 = ntiles * WAVE;
    for (int i = tail0 + (int)blockIdx.x * WAVE + l; i < n;
         i += (int)gridDim.x * WAVE) {
        float X[XW], P[PW], dx[XW];
        #pragma unroll
        for (int j = 0; j < XW; ++j) X[j] = x[(size_t)i * XW + j];
        #pragma unroll
        for (int j = 0; j < PW; ++j) P[j] = params[(size_t)i * PW + j];
        dxdt(X, P, action_ins[i], action_CHO[i], last_Qsto[i],
             last_foodtaken[i], dx);
        #pragma unroll
        for (int j = 0; j < XW; ++j) out[(size_t)i * XW + j] = dx[j];
    }
}

extern "C" void kernel_launch(void* const* d_in, const int* in_sizes, int n_in,
                              void* d_out, int out_size, void* d_ws, size_t ws_size,
                              hipStream_t stream) {
    const float* x      = (const float*)d_in[0];
    const float* params = (const float*)d_in[1];
    const float* ai     = (const float*)d_in[2];
    const float* cho    = (const float*)d_in[3];
    const float* lq     = (const float*)d_in[4];
    const float* lf     = (const float*)d_in[5];
    float* out = (float*)d_out;

    const int n = in_sizes[0] / XW;          // number of patients
    const int ntiles = n / WAVE;
    int grid = ntiles > 0 ? (ntiles < NBLOCK ? ntiles : NBLOCK) : 1;
    t1d_kernel<<<grid, WAVE, 0, stream>>>(x, params, ai, cho, lq, lf, out, n);
}

// Round 7
// 229.197 us; speedup vs baseline: 1.0973x; 1.0228x over previous
//
#include <hip/hip_runtime.h>
#include <math.h>

#define WAVE 64
#define XW 13
#define PW 30

// clang native vector: required by __builtin_nontemporal_load/store
// (HIP_vector_type float4 is rejected). Same 16B codegen.
typedef float f4 __attribute__((ext_vector_type(4)));

// Per-patient derivative. X[13] states, P[30] params (column order per reference).
__device__ __forceinline__ void dxdt(const float* X, const float* P,
                                     float ai, float cho, float lq, float lf,
                                     float* dx)
{
    const float BW = P[0],  KMAX = P[1],  B   = P[2],  D   = P[3],  KMIN = P[4];
    const float KABS = P[5], F   = P[6],  KP1 = P[7],  KP2 = P[8],  KP3  = P[9];
    const float FSNC = P[10], KE1 = P[11], KE2 = P[12], K1 = P[13], K2   = P[14];
    const float VM0 = P[15], VMX = P[16], KM0 = P[17], M1 = P[18], M2   = P[19];
    const float M4  = P[20], KA1 = P[21], KA2 = P[22], VI = P[23], P2U  = P[24];
    const float IB  = P[25], KI  = P[26], M30 = P[27], KD = P[28], KSC  = P[29];

    const float f_insulin = ai * 6000.0f / BW;
    const float qsto = X[0] + X[1];
    const float Dbar = lq + lf;

    dx[0] = -KMAX * X[0] + cho * 1000.0f;

    const float inv_dbar = 1.0f / (Dbar + 1e-7f);
    const float aa = 2.5f / (1.0f - B) * inv_dbar;
    const float cc = 2.5f / D * inv_dbar;
    const float kgut_true = KMIN + (KMAX - KMIN) * 0.5f *
        (tanhf(aa * (qsto - B * Dbar)) - tanhf(cc * (qsto - D * Dbar)) + 2.0f);
    const float kgut = (Dbar > 0.0f) ? kgut_true : KMAX;

    dx[1] = KMAX * X[0] - X[1] * kgut;
    dx[2] = kgut * X[1] - KABS * X[2];

    const float Rat  = F * KABS * X[2] / BW;
    const float EGPt = KP1 - KP2 * X[3] - KP3 * X[8];
    const float Et   = (X[3] > KE2) ? KE1 * (X[3] - KE2) : 0.0f;
    const float d3 = fmaxf(EGPt, 0.0f) + Rat - FSNC - Et - K1 * X[3] + K2 * X[4];
    dx[3] = (X[3] >= 0.0f) ? d3 : 0.0f;

    const float Vmt  = VM0 + VMX * X[6];
    const float Uidt = Vmt * X[4] / (KM0 + X[4]);
    const float d4 = -Uidt + K1 * X[3] - K2 * X[4];
    dx[4] = (X[4] >= 0.0f) ? d4 : 0.0f;

    const float d5 = -(M2 + M4) * X[5] + M1 * X[9] + KA1 * X[10] + KA2 * X[11];
    const float It = X[5] / VI;
    dx[5] = (X[5] >= 0.0f) ? d5 : 0.0f;

    dx[6] = -P2U * X[6] + P2U * (It - IB);
    dx[7] = -KI * (X[7] - It);
    dx[8] = -KI * (X[8] - X[7]);

    const float d9 = -(M1 + M30) * X[9] + M2 * X[5];
    dx[9] = (X[9] >= 0.0f) ? d9 : 0.0f;

    const float d10 = f_insulin - (KA1 + KD) * X[10];
    dx[10] = (X[10] >= 0.0f) ? d10 : 0.0f;

    const float d11 = KD * X[10] - KA2 * X[11];
    dx[11] = (X[11] >= 0.0f) ? d11 : 0.0f;

    const float d12 = -KSC * X[12] + KSC * X[3];
    dx[12] = (X[12] >= 0.0f) ? d12 : 0.0f;
}

// R12: 3-way discriminator. Identical memory semantics to R11 (all streams
// nontemporal, f4 16B access, LDS transpose) but NON-persistent: one tile per
// block, grid=16384, dense in-order dispatch (R5 structure + nt).
// Hypotheses: (1) persistent waves drift out of phase -> fragmented read
// window -> poor DRAM locality; dense dispatch keeps the active address
// window compact (how fill/copy hit 6.3-6.85 TB/s) -> t1d ~50us.
// (2) persistence/prefetch was load-bearing -> regress to ~85us.
// (3) ~3.6 TB/s is this pattern's ceiling -> flat ~70us.
// Spill sentinel: WRITE_SIZE must stay 53248 KiB, VGPR ~52-64, 0 LDS conflicts.
__global__ __launch_bounds__(WAVE, 2) void t1d_kernel(
    const float* __restrict__ x,
    const float* __restrict__ params,
    const float* __restrict__ action_ins,
    const float* __restrict__ action_CHO,
    const float* __restrict__ last_Qsto,
    const float* __restrict__ last_foodtaken,
    float* __restrict__ out, int n)
{
    __shared__ __align__(16) float xb[WAVE * XW];   // 3328 B, doubles as out staging
    __shared__ __align__(16) float pb[WAVE * PW];   // 7680 B

    const int l = threadIdx.x;        // lane 0..63
    const size_t base = (size_t)blockIdx.x * WAVE;
    f4* xl4 = (f4*)xb;
    f4* pl4 = (f4*)pb;

    if (base + WAVE <= (size_t)n) {
        const f4* xg = (const f4*)(x + base * XW);       // 3328B-aligned
        const f4* pg = (const f4*)(params + base * PW);  // 7680B-aligned

        // ---- issue ALL 20 independent nt loads (no consumer until drain) ----
        f4 a0 = __builtin_nontemporal_load(xg + l);
        f4 a1 = __builtin_nontemporal_load(xg + l + 64);
        f4 a2 = __builtin_nontemporal_load(xg + l + 128);
        f4 a3;
        if (l < 16) a3 = __builtin_nontemporal_load(xg + 192 + l); // 208 = 3*64+16
        f4 b0 = __builtin_nontemporal_load(pg + l);
        f4 b1 = __builtin_nontemporal_load(pg + l + 64);
        f4 b2 = __builtin_nontemporal_load(pg + l + 128);
        f4 b3 = __builtin_nontemporal_load(pg + l + 192);
        f4 b4 = __builtin_nontemporal_load(pg + l + 256);
        f4 b5 = __builtin_nontemporal_load(pg + l + 320);
        f4 b6 = __builtin_nontemporal_load(pg + l + 384);
        f4 b7;
        if (l < 32) b7 = __builtin_nontemporal_load(pg + 448 + l); // 480 = 7*64+32
        const float ai  = __builtin_nontemporal_load(action_ins + base + l);
        const float cho = __builtin_nontemporal_load(action_CHO + base + l);
        const float lq  = __builtin_nontemporal_load(last_Qsto + base + l);
        const float lf  = __builtin_nontemporal_load(last_foodtaken + base + l);

        // ---- drain to wave-private LDS (fine-grained vmcnt waits) ----
        xl4[l]       = a0;
        xl4[l + 64]  = a1;
        xl4[l + 128] = a2;
        if (l < 16) xl4[192 + l] = a3;
        pl4[l]       = b0;
        pl4[l + 64]  = b1;
        pl4[l + 128] = b2;
        pl4[l + 192] = b3;
        pl4[l + 256] = b4;
        pl4[l + 320] = b5;
        pl4[l + 384] = b6;
        if (l < 32) pl4[448 + l] = b7;

        // same-wave LDS RAW: compiler inserts lgkmcnt, no barrier needed
        float X[XW], P[PW], dx[XW];
        #pragma unroll
        for (int j = 0; j < XW; ++j) X[j] = xb[l * XW + j];   // stride 13: <=2-way, free
        #pragma unroll
        for (int j = 0; j < PW; ++j) P[j] = pb[l * PW + j];   // stride 30: 4-way, cheap

        dxdt(X, P, ai, cho, lq, lf, dx);

        // out through LDS for coalesced 16B nt stores
        #pragma unroll
        for (int j = 0; j < XW; ++j) xb[l * XW + j] = dx[j];
        f4 o0 = xl4[l], o1 = xl4[l + 64], o2 = xl4[l + 128], o3;
        if (l < 16) o3 = xl4[192 + l];
        f4* og = (f4*)(out + base * XW);
        __builtin_nontemporal_store(o0, og + l);
        __builtin_nontemporal_store(o1, og + l + 64);
        __builtin_nontemporal_store(o2, og + l + 128);
        if (l < 16) __builtin_nontemporal_store(o3, og + 192 + l);
    } else {
        // tail block (not hit for N=2^20): scalar path
        const size_t i = base + l;
        if (i < (size_t)n) {
            float X[XW], P[PW], dx[XW];
            #pragma unroll
            for (int j = 0; j < XW; ++j) X[j] = x[i * XW + j];
            #pragma unroll
            for (int j = 0; j < PW; ++j) P[j] = params[i * PW + j];
            dxdt(X, P, action_ins[i], action_CHO[i], last_Qsto[i],
                 last_foodtaken[i], dx);
            #pragma unroll
            for (int j = 0; j < XW; ++j) out[i * XW + j] = dx[j];
        }
    }
}

extern "C" void kernel_launch(void* const* d_in, const int* in_sizes, int n_in,
                              void* d_out, int out_size, void* d_ws, size_t ws_size,
                              hipStream_t stream) {
    const float* x      = (const float*)d_in[0];
    const float* params = (const float*)d_in[1];
    const float* ai     = (const float*)d_in[2];
    const float* cho    = (const float*)d_in[3];
    const float* lq     = (const float*)d_in[4];
    const float* lf     = (const float*)d_in[5];
    float* out = (float*)d_out;

    const int n = in_sizes[0] / XW;          // number of patients
    const int grid = (n + WAVE - 1) / WAVE;
    t1d_kernel<<<grid, WAVE, 0, stream>>>(x, params, ai, cho, lq, lf, out, n);
}